// Round 1
// 119.329 us; speedup vs baseline: 1.0215x; 1.0215x over previous
//
#include <hip/hip_runtime.h>
#include <hip/hip_bf16.h>
#include <stdint.h>

// Problem constants (fixed by reference)
#define B_  4
#define N_  8192
#define M_  8192
#define D_  64
#define NT_ 64    // N_/128
#define RBN ((B_ * N_) / 16)   // 2048 16-row blocks on A side
#define INF_BITS 0x7F800000    // +inf float bits; all stored mins are full squared dists (>=0),
                               // so signed-int atomicMin == float min

typedef __attribute__((ext_vector_type(8))) short bhalf8;   // 8 bf16 (MFMA A/B frag)
typedef __attribute__((ext_vector_type(4))) float f32x4;    // MFMA C/D frag

// ---- workspace layout (bytes) ----
// A'/B': bf16, K=64 only (2 k-steps of 32). Fragment-chunk order:
//   chunk(rb, ks=0..1, lane=q*16+c) = row (rb*16+c), k = ks*32 + q*8 .. +7,
//   at ((rb*2+ks)*64 + lane)*8 elems -> lane-contiguous 1KB loads.
// Norms are NOT carried in K anymore:
//   nA/nB: exact fp32 ||row||^2 per point.
//   row norms enter via the MFMA C-operand (acc = nx - 2x.y, K=64 -> 16 MFMA/process vs 24),
//   col norms are added in the process epilogue from a 4KB LDS broadcast table.
// rowglob/colglob: per-point global mins as float BIT PATTERNS (int), atomicMin-accumulated.
static const size_t OFF_A  = 0;
static const size_t OFF_B  = (size_t)B_ * N_ * D_ * 2;                 // 4,194,304
static const size_t OFF_NA = OFF_B + (size_t)B_ * M_ * D_ * 2;         // 8,388,608
static const size_t OFF_NB = OFF_NA + (size_t)B_ * N_ * 4;             // +128 KB
static const size_t OFF_RG = OFF_NB + (size_t)B_ * M_ * 4;             // +128 KB
static const size_t OFF_CG = OFF_RG + (size_t)B_ * N_ * 4;             // +128 KB
// end: OFF_CG + 128 KB = 8,912,896

__device__ __forceinline__ short bf16bits(float x) {
    union { __hip_bfloat16 h; unsigned short u; } cv;
    cv.h = __float2bfloat16(x);
    return (short)cv.u;
}
__device__ __forceinline__ float min3f(float a, float b, float c) {
    return fminf(fminf(a, b), c);   // -> v_min3_f32
}

// ---------------- prep: K=64 fragment layout + fp32 norms; init global min buffers + out ----------------
__global__ __launch_bounds__(256) void chamfer_prep(
        const float* __restrict__ f, const float* __restrict__ f2,
        unsigned short* __restrict__ Ap, unsigned short* __restrict__ Bp,
        float* __restrict__ nA, float* __restrict__ nB,
        int* __restrict__ minbuf, float* __restrict__ out) {
    const int tid = threadIdx.x;
    const int gid = blockIdx.x * 256 + tid;
    if (gid == 0) out[0] = 0.f;                      // finalize atomicAdds into this
    if (gid < 65536) minbuf[gid] = INF_BITS;         // rowglob(32K ints) + colglob(32K ints)

    const int w = gid >> 6;                          // 16-row block id, 0..4095
    const int lane = tid & 63;
    const int q = lane >> 4, c = lane & 15;
    const bool isA = w < RBN;
    const int rb = isA ? w : w - RBN;
    const float* src = isA ? f : f2;
    unsigned short* dst = isA ? Ap : Bp;
    float* ndst = isA ? nA : nB;
    const float scale = isA ? -2.0f : 1.0f;          // fold the -2 into A; exact in bf16

    const float* row = src + ((size_t)rb * 16 + c) * 64;
    f32x4 u0 = *(const f32x4*)(row + q * 8);
    f32x4 u1 = *(const f32x4*)(row + q * 8 + 4);
    f32x4 u2 = *(const f32x4*)(row + 32 + q * 8);
    f32x4 u3 = *(const f32x4*)(row + 32 + q * 8 + 4);

    float ss = 0.f;
    #pragma unroll
    for (int k = 0; k < 4; k++)
        ss += u0[k] * u0[k] + u1[k] * u1[k] + u2[k] * u2[k] + u3[k] * u3[k];
    ss += __shfl_xor(ss, 16, 64);
    ss += __shfl_xor(ss, 32, 64);                    // full ||row c||^2 in every lane (fp32, exact)

    bhalf8 o0, o1;
    #pragma unroll
    for (int k = 0; k < 4; k++) {
        o0[k]     = bf16bits(u0[k] * scale);
        o0[4 + k] = bf16bits(u1[k] * scale);
        o1[k]     = bf16bits(u2[k] * scale);
        o1[4 + k] = bf16bits(u3[k] * scale);
    }
    if (q == 0) ndst[rb * 16 + c] = ss;              // 16 consecutive floats per wave
    *(bhalf8*)(dst + ((size_t)(rb * 2 + 0) * 64 + lane) * 8) = o0;
    *(bhalf8*)(dst + ((size_t)(rb * 2 + 1) * 64 + lane) * 8) = o1;
}

// ---------------- tile kernel: K=64 wait-free loop, norms via C-init + epilogue add ----------------
// grid (mc=8, nt=64, b=4) = 2048 blocks; wave tile 64 rows x 32 cols/step, 16 steps.
// acc = nx - 2x.y (row norm rides in the MFMA C operand, fp32-exact, loaded once per block).
// sv = acc + ny[col] = full squared distance; row-min and col-min both reduce sv,
// so the int-bits atomicMin trick stays valid (sv >= 0) and finalize is unchanged.
__global__ __launch_bounds__(256) void chamfer_tile(
        const unsigned short* __restrict__ Ap, const unsigned short* __restrict__ Bp,
        const float* __restrict__ nA, const float* __restrict__ nB,
        int* __restrict__ rowglob, int* __restrict__ colglob) {
    const int mc = blockIdx.x;   // 0..7 : 8-tile mt chunk
    const int nt = blockIdx.y;   // 0..63
    const int b  = blockIdx.z;   // 0..3
    const int tid = threadIdx.x;
    const int wave = tid >> 6, lane = tid & 63;
    const int wr = wave >> 1, wc = wave & 1;
    const int q = lane >> 4, c = lane & 15;

    // q-slot col mins: stride 1064 words (1064%32==8 -> bank 8q+col: <=2-way, free)
    __shared__ int colmin[4][1064];   // [q][mtl*132 + col], col 0..127, mtl 0..7
    __shared__ int rowmin[128];
    __shared__ float nyb[1024];       // this block's 1024 col norms (fp32)

    // stage col norms (4KB) + init min buffers
    *(f32x4*)&nyb[tid * 4] = *(const f32x4*)(nB + (size_t)b * 8192 + mc * 1024 + tid * 4);
    #pragma unroll
    for (int k = 0; k < 17; k++) {
        int idx = k * 256 + tid;
        if (idx < 4256) ((int*)colmin)[idx] = INF_BITS;
    }
    if (tid < 128) rowmin[tid] = INF_BITS;
    __syncthreads();

    // A fragments: rows nt*128 + wr*64 + i*16 + c, 2 k-steps. Loaded once.
    const int rbA0 = b * 512 + nt * 8 + wr * 4;
    bhalf8 af[4][2];
    #pragma unroll
    for (int i = 0; i < 4; i++)
        #pragma unroll
        for (int ks = 0; ks < 2; ks++)
            af[i][ks] = *(const bhalf8*)(Ap + ((size_t)((rbA0 + i) * 2 + ks) * 64 + lane) * 8);

    // C-init row norms: acc reg r of tile i is row i*16 + q*4 + r -> one f32x4 load per i
    f32x4 cnx[4];
    {
        const float* nrow = nA + (size_t)b * 8192 + nt * 128 + wr * 64 + q * 4;
        #pragma unroll
        for (int i = 0; i < 4; i++)
            cnx[i] = *(const f32x4*)(nrow + i * 16);
    }

    f32x4 rv[4];                 // running row-min, rows i*16+q*4+r (this wave's 64 rows)
    #pragma unroll
    for (int i = 0; i < 4; i++) rv[i] = (f32x4){3.0e38f, 3.0e38f, 3.0e38f, 3.0e38f};

    // step s: mt = mc*8 + s/2, rbB = b*512 + mt*8 + wc*4 + (s&1)*2; cols = wc*64+(s&1)*32+jj*16+c
    // pointers in shorts: rb stride 1024; per 2 steps advance 8 rb = 8192 shorts.
    const unsigned short* pE = Bp + (size_t)(b * 512 + mc * 64 + wc * 4) * 1024 + lane * 8;
    const unsigned short* pO = pE + 2048;   // (s&1)=1 -> +2 rb

    auto loadB = [&](const unsigned short* p, bhalf8 (&bf)[2][2]) {
        #pragma unroll
        for (int jj = 0; jj < 2; jj++)
            #pragma unroll
            for (int ks = 0; ks < 2; ks++)
                bf[jj][ks] = *(const bhalf8*)(p + jj * 1024 + ks * 512);
    };

    auto process = [&](int mtl, int half, bhalf8 (&bf)[2][2]) {
        f32x4 acc[4][2];
        #pragma unroll
        for (int i = 0; i < 4; i++)
            #pragma unroll
            for (int jj = 0; jj < 2; jj++)
                acc[i][jj] = __builtin_amdgcn_mfma_f32_16x16x32_bf16(af[i][0], bf[jj][0], cnx[i], 0, 0, 0);
        #pragma unroll
        for (int i = 0; i < 4; i++)
            #pragma unroll
            for (int jj = 0; jj < 2; jj++)
                acc[i][jj] = __builtin_amdgcn_mfma_f32_16x16x32_bf16(af[i][1], bf[jj][1], acc[i][jj], 0, 0, 0);
        // acc[i][jj][r] = nx - 2x.y for (row nt*128+wr*64+i*16+q*4+r, col (mc*8+mtl)*128+wc*64+half*32+jj*16+c)

        // col norms: per-lane scalars, 4-way same-address LDS broadcast (free)
        const int cb = mtl * 128 + wc * 64 + half * 32 + c;
        const float ny0 = nyb[cb];
        const float ny1 = nyb[cb + 16];

        // sv = full squared distance; row-min fused as min3(sv0, sv1, rv)
        float sv[4][2][4];
        #pragma unroll
        for (int i = 0; i < 4; i++)
            #pragma unroll
            for (int r = 0; r < 4; r++) {
                sv[i][0][r] = acc[i][0][r] + ny0;
                sv[i][1][r] = acc[i][1][r] + ny1;
                rv[i][r] = min3f(sv[i][0][r], sv[i][1][r], rv[i][r]);
            }

        // col-min over this lane's 16 rows: balanced min3 tree (8 ops), then 1 ds_min per jj
        #pragma unroll
        for (int jj = 0; jj < 2; jj++) {
            float t0 = min3f(sv[0][jj][0], sv[0][jj][1], sv[0][jj][2]);
            float t1 = min3f(sv[0][jj][3], sv[1][jj][0], sv[1][jj][1]);
            float t2 = min3f(sv[1][jj][2], sv[1][jj][3], sv[2][jj][0]);
            float t3 = min3f(sv[2][jj][1], sv[2][jj][2], sv[2][jj][3]);
            float t4 = min3f(sv[3][jj][0], sv[3][jj][1], sv[3][jj][2]);
            float t  = fminf(min3f(t0, t1, t2), min3f(t3, t4, sv[3][jj][3]));
            atomicMin(&colmin[q][mtl * 132 + wc * 64 + half * 32 + jj * 16 + c], __float_as_int(t));
        }
    };

    bhalf8 bf0[2][2], bf1[2][2];
    loadB(pE, bf0);
    #pragma unroll 1
    for (int mtl = 0; mtl < 8; mtl++) {
        loadB(pO, bf1);
        process(mtl, 0, bf0);
        pE += 8192;
        if (mtl < 7) loadB(pE, bf0);
        process(mtl, 1, bf1);
        pO += 8192;
    }

    // flush register row-mins to LDS, then one global atomicMin per row / per col
    #pragma unroll
    for (int i = 0; i < 4; i++)
        #pragma unroll
        for (int r = 0; r < 4; r++)
            atomicMin(&rowmin[wr * 64 + i * 16 + q * 4 + r], __float_as_int(rv[i][r]));
    __syncthreads();

    if (tid < 128)
        atomicMin(&rowglob[(size_t)(b * 64 + nt) * 128 + tid], rowmin[tid]);
    #pragma unroll
    for (int k = 0; k < 4; k++) {
        const int idx = k * 256 + tid;       // 0..1023 = mtl*128 + col
        const int mtl = idx >> 7, col = idx & 127;
        int m = min(min(colmin[0][mtl * 132 + col], colmin[1][mtl * 132 + col]),
                    min(colmin[2][mtl * 132 + col], colmin[3][mtl * 132 + col]));
        atomicMin(&colglob[(size_t)(b * 64 + mc * 8 + mtl) * 128 + col], m);
    }
}

// ---------------- finalize: mean of rowglob + colglob (256 KB total) ----------------
__global__ __launch_bounds__(256) void chamfer_finalize(
        const int* __restrict__ rowglob, const int* __restrict__ colglob,
        float* __restrict__ out) {
    const int gid = blockIdx.x * 256 + threadIdx.x;   // 64 blocks -> 16384 threads
    float s = 0.f;
    #pragma unroll
    for (int k = 0; k < 2; k++) {
        s += __int_as_float(rowglob[gid + k * 16384]) * (1.0f / ((float)B_ * (float)N_));
        s += __int_as_float(colglob[gid + k * 16384]) * (1.0f / ((float)B_ * (float)M_));
    }
    __shared__ float sb[256];
    const int tid = threadIdx.x;
    sb[tid] = s;
    __syncthreads();
    for (int st = 128; st > 0; st >>= 1) {
        if (tid < st) sb[tid] += sb[tid + st];
        __syncthreads();
    }
    if (tid == 0) atomicAdd(out, sb[0]);
}

extern "C" void kernel_launch(void* const* d_in, const int* in_sizes, int n_in,
                              void* d_out, int out_size, void* d_ws, size_t ws_size,
                              hipStream_t stream) {
    const float* f  = (const float*)d_in[0];
    const float* f2 = (const float*)d_in[1];
    char* ws = (char*)d_ws;
    unsigned short* Ap = (unsigned short*)(ws + OFF_A);
    unsigned short* Bp = (unsigned short*)(ws + OFF_B);
    float* nA    = (float*)(ws + OFF_NA);
    float* nB    = (float*)(ws + OFF_NB);
    int* rowglob = (int*)(ws + OFF_RG);
    int* colglob = (int*)(ws + OFF_CG);
    float* out   = (float*)d_out;

    // prep: K=64 fragment layout + fp32 norms; inits rowglob/colglob/out
    chamfer_prep<<<dim3(1024), dim3(256), 0, stream>>>(f, f2, Ap, Bp, nA, nB, rowglob, out);

    // main: 2048 blocks, wait-free 16-step loop, 16 MFMA/process (K=64)
    chamfer_tile<<<dim3(8, NT_, B_), dim3(256), 0, stream>>>(Ap, Bp, nA, nB, rowglob, colglob);

    // finalize: 256 KB read + block sums -> scalar
    chamfer_finalize<<<dim3(64), dim3(256), 0, stream>>>(rowglob, colglob, out);
}